// Round 2
// baseline (180.010 us; speedup 1.0000x reference)
//
#include <hip/hip_runtime.h>
#include <stdint.h>

#define HH 512
#define WW 512
#define HW (HH * WW)          // 262144 pixels per image
#define WPR 8                 // u64 words per row (512 bits)
#define NWORDS (HH * WPR)     // 4096 words per image
#define NTHREADS 1024
#define WPT (NWORDS / NTHREADS) // 4
#define NB 16                 // batch

typedef unsigned long long u64;

__device__ __forceinline__ u64 ldw(const u64* M, int r, int c) {
    return (r < 0 || r >= HH || c < 0 || c >= WPR) ? 0ULL : M[r * WPR + c];
}

// One Zhang-Suen sub-step for word (r,c). Bit k = pixel col c*64+k.
// cc (the word itself) passed in to avoid a duplicate LDS read.
__device__ __forceinline__ u64 zs_word(const u64* M, u64 cc, int r, int c, int step) {
    u64 nm = ldw(M, r - 1, c - 1), nc = ldw(M, r - 1, c), np = ldw(M, r - 1, c + 1);
    u64 cm = ldw(M, r,     c - 1),                        cp = ldw(M, r,     c + 1);
    u64 sm = ldw(M, r + 1, c - 1), sc = ldw(M, r + 1, c), sp = ldw(M, r + 1, c + 1);

    u64 P2 = nc;
    u64 P3 = (nc >> 1) | (np << 63);
    u64 P4 = (cc >> 1) | (cp << 63);
    u64 P5 = (sc >> 1) | (sp << 63);
    u64 P6 = sc;
    u64 P7 = (sc << 1) | (sm >> 63);
    u64 P8 = (cc << 1) | (cm >> 63);
    u64 P9 = (nc << 1) | (nm >> 63);

    u64 ab = P2 ^ P3;
    u64 s1 = ab ^ P4, c1 = (P2 & P3) | (ab & P4);
    u64 de = P5 ^ P6;
    u64 s2 = de ^ P7, c2 = (P5 & P6) | (de & P7);
    u64 s3 = P8 ^ P9, c3 = P8 & P9;
    u64 gh = s1 ^ s2;
    u64 b0 = gh ^ s3, c4 = (s1 & s2) | (gh & s3);
    u64 ij = c1 ^ c2;
    u64 s4 = ij ^ c3, c5 = (c1 & c2) | (ij & c3);
    u64 b1 = s4 ^ c4, c6 = s4 & c4;
    u64 b2 = c5 ^ c6, b3 = c5 & c6;

    u64 Bge2 = b1 | b2 | b3;
    u64 Ble6 = ~(b3 | (b2 & b1 & b0));

    u64 a1, a2, t;
    t = ~P2 & P3; a1 = t; a2 = 0ULL;
    t = ~P3 & P4; a2 |= a1 & t; a1 |= t;
    t = ~P4 & P5; a2 |= a1 & t; a1 |= t;
    t = ~P5 & P6; a2 |= a1 & t; a1 |= t;
    t = ~P6 & P7; a2 |= a1 & t; a1 |= t;
    t = ~P7 & P8; a2 |= a1 & t; a1 |= t;
    t = ~P8 & P9; a2 |= a1 & t; a1 |= t;
    t = ~P9 & P2; a2 |= a1 & t; a1 |= t;
    u64 Aeq1 = a1 & ~a2;

    u64 sccond;
    if (step == 0) sccond = ~(P2 & P4 & P6) & ~(P4 & P6 & P8);
    else           sccond = ~(P2 & P4 & P8) & ~(P2 & P6 & P8);

    return cc & ~(Bge2 & Ble6 & Aeq1 & sccond);
}

// radius-3 disk dilation over full image in LDS (row/col bounds via ldw)
__device__ __forceinline__ u64 dil3f(const u64* M, int r, int c) {
    u64 cm = ldw(M, r, c - 1), cc = ldw(M, r, c), cp = ldw(M, r, c + 1);
    u64 h = cc
          | (cc >> 1) | (cp << 63)
          | (cc >> 2) | (cp << 62)
          | (cc >> 3) | (cp << 61)
          | (cc << 1) | (cm >> 63)
          | (cc << 2) | (cm >> 62)
          | (cc << 3) | (cm >> 61);
    u64 um = ldw(M, r - 1, c - 1) | ldw(M, r + 1, c - 1) | ldw(M, r - 2, c - 1) | ldw(M, r + 2, c - 1);
    u64 uc = ldw(M, r - 1, c    ) | ldw(M, r + 1, c    ) | ldw(M, r - 2, c    ) | ldw(M, r + 2, c    );
    u64 up = ldw(M, r - 1, c + 1) | ldw(M, r + 1, c + 1) | ldw(M, r - 2, c + 1) | ldw(M, r + 2, c + 1);
    h |= uc
       | (uc >> 1) | (up << 63)
       | (uc >> 2) | (up << 62)
       | (uc << 1) | (um >> 63)
       | (uc << 2) | (um >> 62);
    h |= ldw(M, r - 3, c) | ldw(M, r + 3, c);
    return h;
}

// ---------------- pack: full-GPU binarize (2048 blocks x 256 threads) --------
// Each thread packs 16 consecutive pixels -> one ushort of the bit image.
// Block 0 also zeroes cnt[64] + pairflag[16] + done2[1] (81 ints) before skel.
__global__ __launch_bounds__(256)
void pack_kernel(const float* __restrict__ y_pred,
                 const float* __restrict__ y_true,
                 u64* __restrict__ bits /* [32][NWORDS], reused as skel */,
                 int* __restrict__ cnt /* 64 cnt + 16 pairflag + 1 done2 */) {
    int tid = threadIdx.x;
    if (blockIdx.x == 0 && tid < 4 * NB + 17) cnt[tid] = 0;

    int t = blockIdx.x * 256 + tid;                      // ushort index 0..524287
    size_t g0 = (size_t)t * 16;                          // pixel index, concat space
    const float* src;
    size_t off;
    if (g0 < (size_t)NB * HW) { src = y_pred; off = g0; }
    else                      { src = y_true; off = g0 - (size_t)NB * HW; }
    const float4* s4 = (const float4*)(src + off);       // 64B-aligned (16-float mult)
    float4 a = s4[0];
    float4 b = s4[1];
    float4 c = s4[2];
    float4 d = s4[3];
    unsigned m =
        ((unsigned)(a.x > 0.5f) << 0)  | ((unsigned)(a.y > 0.5f) << 1)  |
        ((unsigned)(a.z > 0.5f) << 2)  | ((unsigned)(a.w > 0.5f) << 3)  |
        ((unsigned)(b.x > 0.5f) << 4)  | ((unsigned)(b.y > 0.5f) << 5)  |
        ((unsigned)(b.z > 0.5f) << 6)  | ((unsigned)(b.w > 0.5f) << 7)  |
        ((unsigned)(c.x > 0.5f) << 8)  | ((unsigned)(c.y > 0.5f) << 9)  |
        ((unsigned)(c.z > 0.5f) << 10) | ((unsigned)(c.w > 0.5f) << 11) |
        ((unsigned)(d.x > 0.5f) << 12) | ((unsigned)(d.y > 0.5f) << 13) |
        ((unsigned)(d.z > 0.5f) << 14) | ((unsigned)(d.w > 0.5f) << 15);
    ((unsigned short*)bits)[t] = (unsigned short)m;
}

// ---------------- mega kernel: skeletonize + count + reduce ------------------
// 32 blocks, one image each. After thinning, pair (b, b+16) synchronizes via a
// no-spin last-arriver chain: the SECOND block of each pair (atomicAdd old==1)
// counts TP/FP/FN for the pair; the LAST counting block (done2 old==15)
// computes the final [correctness, completeness, quality] means.
__global__ __launch_bounds__(NTHREADS)
void skel_kernel(u64* __restrict__ bits /* in: packed bits, out: skeleton */,
                 int* __restrict__ cnt, int* __restrict__ pairflag,
                 int* __restrict__ done2, float* __restrict__ out) {
    __shared__ u64 Mb[2][NWORDS];           // 64 KB
    __shared__ unsigned int Cpb[2][HH + 2]; // padded row change masks
    __shared__ int s_any[3];
    __shared__ int s_role;
    __shared__ int s_acc[4];

    int bx = blockIdx.x;
    int tid = threadIdx.x;
    int lane = tid & 63;

    u64* gm = bits + (size_t)bx * NWORDS;

    {   // load packed image: 32 KB, 16B/lane coalesced
        const ulonglong2* s2 = (const ulonglong2*)gm;
        ulonglong2* m2 = (ulonglong2*)Mb[0];
        #pragma unroll
        for (int k = 0; k < 2; ++k) {
            int i = k * NTHREADS + tid;
            m2[i] = s2[i];
        }
    }

    // init: interior rows fully dirty (forces first two sub-steps)
    for (int i = tid; i < HH + 2; i += NTHREADS) {
        Cpb[0][i] = (i >= 1 && i <= HH) ? 0x1FEu : 0u;
        Cpb[1][i] = 0u;                     // boundaries stay 0 forever
    }
    if (tid < 3) s_any[tid] = 0;
    if (tid < 4) s_acc[tid] = 0;

    unsigned dl[WPT];                       // row-owner's "last sub-step" mask
    u64 balPrev[WPT];                       // per-word change mask of prev phase
    #pragma unroll
    for (int k = 0; k < WPT; ++k) { dl[k] = 0x1FEu; balPrev[k] = ~0ULL; }

    int it = 0;
    bool done = false;
    for (;;) {
        for (int step = 0; step < 2; ++step) {
            __syncthreads();                // orders prior phase's M/Cp/s_any writes
            if (step == 0 && it > 0) {
                if (s_any[(it + 2) % 3] == 0) { done = true; break; }  // prev iter clean
            }
            const u64* Ms = Mb[step];
            u64* Md = Mb[step ^ 1];
            const unsigned* CpS = Cpb[step];
            unsigned* CpD = Cpb[step ^ 1];
            bool anyc = false;
            #pragma unroll
            for (int k = 0; k < WPT; ++k) {
                int wi = k * NTHREADS + tid;
                int r = wi >> 3, c = wi & 7;
                unsigned need = ((CpS[r] | CpS[r + 1] | CpS[r + 2]) >> c) & 7u;
                u64 cur = Ms[wi];
                u64 x = cur;
                bool chg = false;
                if (need) {
                    x = zs_word(Ms, cur, r, c, step);
                    chg = (x != cur);
                }
                u64 bal = __ballot(chg);    // wave's 64 bits = 8 rows x 8 cols
                anyc |= (bal != 0);
                // Md holds the state from 2 phases ago; store only if the word
                // changed this phase or last phase (else already correct).
                if (((bal | balPrev[k]) >> lane) & 1) Md[wi] = x;
                balPrev[k] = bal;
                if ((lane & 7) == 0) {      // one owner lane per row
                    unsigned byte = ((unsigned)(bal >> lane) & 0xFFu) << 1;
                    CpD[(wi >> 3) + 1] = byte | dl[k]; // union of last two sub-steps
                    dl[k] = byte;
                }
            }
            if (anyc) s_any[it % 3] = 1;                     // benign same-value race
            if (step == 1 && tid == 0) s_any[(it + 1) % 3] = 0; // reset next iter's slot
        }
        if (done) break;                    // uniform across block
        ++it;
    }

    {   // publish skeleton (state is in Mb[0] — break happens at step 0)
        ulonglong2* d2 = (ulonglong2*)gm;
        const ulonglong2* m2 = (const ulonglong2*)Mb[0];
        #pragma unroll
        for (int k = 0; k < 2; ++k) {
            int i = k * NTHREADS + tid;
            d2[i] = m2[i];
        }
    }
    __syncthreads();                        // all stores issued block-wide
    if (tid == 0) {
        __threadfence();                    // release own skeleton device-wide
        s_role = atomicAdd(&pairflag[bx & (NB - 1)], 1);  // 0=first, 1=second
    }
    __syncthreads();
    if (s_role == 0) return;                // partner will do the counting
    __threadfence();                        // acquire partner's published data

    // ---- count: own skeleton in Mb[0], partner's loaded into Mb[1] ----
    {
        const ulonglong2* p2 = (const ulonglong2*)(bits + (size_t)(bx ^ NB) * NWORDS);
        ulonglong2* m2 = (ulonglong2*)Mb[1];
        #pragma unroll
        for (int k = 0; k < 2; ++k) {
            int i = k * NTHREADS + tid;
            m2[i] = p2[i];
        }
    }
    __syncthreads();
    const u64* P = (bx < NB) ? Mb[0] : Mb[1];   // pred skeleton
    const u64* G = (bx < NB) ? Mb[1] : Mb[0];   // gt skeleton

    int cp = 0, cg = 0, tp = 0, fnh = 0;
    #pragma unroll
    for (int k = 0; k < WPT; ++k) {
        int wi = k * NTHREADS + tid;
        int r = wi >> 3, c = wi & 7;
        u64 pw = P[wi], gw = G[wi];
        cp  += __popcll(pw);
        cg  += __popcll(gw);
        tp  += __popcll(pw & dil3f(G, r, c));
        fnh += __popcll(gw & dil3f(P, r, c));
    }
    #pragma unroll
    for (int o = 32; o > 0; o >>= 1) {
        cp  += __shfl_down(cp, o);
        cg  += __shfl_down(cg, o);
        tp  += __shfl_down(tp, o);
        fnh += __shfl_down(fnh, o);
    }
    if (lane == 0) {
        atomicAdd(&s_acc[0], cp);
        atomicAdd(&s_acc[1], cg);
        atomicAdd(&s_acc[2], tp);
        atomicAdd(&s_acc[3], fnh);
    }
    __syncthreads();
    int b = bx & (NB - 1);
    if (tid < 4) atomicAdd(&cnt[b * 4 + tid], s_acc[tid]);
    __syncthreads();
    if (tid == 0) {
        __threadfence();                    // release this pair's counts
        s_role = (atomicAdd(done2, 1) == NB - 1) ? 2 : 0;
    }
    __syncthreads();
    if (s_role != 2) return;                // not the last pair
    __threadfence();                        // acquire all pairs' counts

    if (tid < 3) {
        float s = 0.0f;
        for (int i = 0; i < NB; ++i) {
            float c0 = (float)atomicAdd(&cnt[i * 4 + 0], 0);
            float c1 = (float)atomicAdd(&cnt[i * 4 + 1], 0);
            float TP = (float)atomicAdd(&cnt[i * 4 + 2], 0);
            float c3 = (float)atomicAdd(&cnt[i * 4 + 3], 0);
            float FP = c0 - TP;
            float FN = c1 - c3;
            float v = (tid == 0) ? TP / (TP + FP + 1e-12f)
                    : (tid == 1) ? TP / (TP + FN + 1e-12f)
                                 : TP / (TP + FP + FN + 1e-12f);
            s += v;
        }
        out[tid] = s * (1.0f / NB);
    }
}

extern "C" void kernel_launch(void* const* d_in, const int* in_sizes, int n_in,
                              void* d_out, int out_size, void* d_ws, size_t ws_size,
                              hipStream_t stream) {
    (void)in_sizes; (void)n_in; (void)out_size; (void)ws_size;
    const float* y_pred = (const float*)d_in[0];
    const float* y_true = (const float*)d_in[1];
    float* out = (float*)d_out;

    u64* bits = (u64*)d_ws;                               // 1 MB: packed, then skeleton
    int* cnt = (int*)((char*)d_ws + (size_t)2 * NB * NWORDS * sizeof(u64));
    int* pairflag = cnt + 4 * NB;                         // 16 ints
    int* done2 = cnt + 4 * NB + 16;                       // 1 int

    hipLaunchKernelGGL(pack_kernel, dim3(2 * NB * HW / 16 / 256), dim3(256), 0, stream,
                       y_pred, y_true, bits, cnt);
    hipLaunchKernelGGL(skel_kernel, dim3(2 * NB), dim3(NTHREADS), 0, stream,
                       bits, cnt, pairflag, done2, out);
}

// Round 4
// 115.945 us; speedup vs baseline: 1.5526x; 1.5526x over previous
//
#include <hip/hip_runtime.h>
#include <stdint.h>

#define HH 512
#define WW 512
#define HW (HH * WW)          // 262144 pixels per image
#define WPR 8                 // u64 words per row (global layout)
#define NWORDS (HH * WPR)     // 4096 words per image
#define NTHREADS 1024
#define NB 16                 // batch

// padded LDS layout for skel: rows -1..512, cols -1..8 (stride 10 words)
#define LSTR 10
#define LROWS (HH + 2)        // 514
#define LWORDS (LROWS * LSTR) // 5140 words = 41120 B per buffer

typedef unsigned long long u64;

// Zhang-Suen sub-step core on prebuilt neighbor views (bit k = pixel col k).
__device__ __forceinline__ u64 zs_core(u64 cc, u64 P2, u64 P3, u64 P4, u64 P5,
                                       u64 P6, u64 P7, u64 P8, u64 P9, int step) {
    u64 ab = P2 ^ P3;
    u64 s1 = ab ^ P4, c1 = (P2 & P3) | (ab & P4);
    u64 de = P5 ^ P6;
    u64 s2 = de ^ P7, c2 = (P5 & P6) | (de & P7);
    u64 s3 = P8 ^ P9, c3 = P8 & P9;
    u64 gh = s1 ^ s2;
    u64 b0 = gh ^ s3, c4 = (s1 & s2) | (gh & s3);
    u64 ij = c1 ^ c2;
    u64 s4 = ij ^ c3, c5 = (c1 & c2) | (ij & c3);
    u64 b1 = s4 ^ c4, c6 = s4 & c4;
    u64 b2 = c5 ^ c6, b3 = c5 & c6;

    u64 Bge2 = b1 | b2 | b3;
    u64 Ble6 = ~(b3 | (b2 & b1 & b0));

    u64 a1, a2, t;
    t = ~P2 & P3; a1 = t; a2 = 0ULL;
    t = ~P3 & P4; a2 |= a1 & t; a1 |= t;
    t = ~P4 & P5; a2 |= a1 & t; a1 |= t;
    t = ~P5 & P6; a2 |= a1 & t; a1 |= t;
    t = ~P6 & P7; a2 |= a1 & t; a1 |= t;
    t = ~P7 & P8; a2 |= a1 & t; a1 |= t;
    t = ~P8 & P9; a2 |= a1 & t; a1 |= t;
    t = ~P9 & P2; a2 |= a1 & t; a1 |= t;
    u64 Aeq1 = a1 & ~a2;

    u64 sccond = (step == 0) ? ~((P4 & P6) & (P2 | P8))
                             : ~((P2 & P8) & (P4 | P6));

    return cc & ~(Bge2 & Ble6 & Aeq1 & sccond);
}

// ---------------- pack: full-GPU binarize (2048 blocks x 256 threads) --------
__global__ __launch_bounds__(256)
void pack_kernel(const float* __restrict__ y_pred,
                 const float* __restrict__ y_true,
                 u64* __restrict__ bits /* [32][NWORDS], reused as skel */,
                 int* __restrict__ cnt /* [16][4] */) {
    int tid = threadIdx.x;
    if (blockIdx.x == 0 && tid < 4 * NB) cnt[tid] = 0;   // zero counters

    int t = blockIdx.x * 256 + tid;                      // ushort index 0..524287
    size_t g0 = (size_t)t * 16;                          // pixel index, concat space
    const float* src;
    size_t off;
    if (g0 < (size_t)NB * HW) { src = y_pred; off = g0; }
    else                      { src = y_true; off = g0 - (size_t)NB * HW; }
    const float4* s4 = (const float4*)(src + off);       // 64B-aligned
    float4 a = s4[0];
    float4 b = s4[1];
    float4 c = s4[2];
    float4 d = s4[3];
    unsigned m =
        ((unsigned)(a.x > 0.5f) << 0)  | ((unsigned)(a.y > 0.5f) << 1)  |
        ((unsigned)(a.z > 0.5f) << 2)  | ((unsigned)(a.w > 0.5f) << 3)  |
        ((unsigned)(b.x > 0.5f) << 4)  | ((unsigned)(b.y > 0.5f) << 5)  |
        ((unsigned)(b.z > 0.5f) << 6)  | ((unsigned)(b.w > 0.5f) << 7)  |
        ((unsigned)(c.x > 0.5f) << 8)  | ((unsigned)(c.y > 0.5f) << 9)  |
        ((unsigned)(c.z > 0.5f) << 10) | ((unsigned)(c.w > 0.5f) << 11) |
        ((unsigned)(d.x > 0.5f) << 12) | ((unsigned)(d.y > 0.5f) << 13) |
        ((unsigned)(d.z > 0.5f) << 14) | ((unsigned)(d.w > 0.5f) << 15);
    ((unsigned short*)bits)[t] = (unsigned short)m;
}

// ---------------- skeletonize: one block per mask (32 blocks) ----------------
// Thread t owns 4 vertically-adjacent words: rowblock rb = t>>3 (rows 4rb..4rb+3),
// col c = t&7. Guard-padded LDS removes all bounds checks; east/west shifted row
// views are built once per row and shared by the 4 words. One barrier per phase.
__global__ __launch_bounds__(NTHREADS, 4)
void skel_kernel(u64* __restrict__ bits /* in: packed bits, out: skeleton */) {
    __shared__ u64 Mb[2][LWORDS];           // 2 x 41120 B
    __shared__ unsigned int Cpb[2][130];    // rowblock change masks (+pad)
    __shared__ int s_any[3];

    int bx = blockIdx.x;
    int tid = threadIdx.x;
    int lane = tid & 63;
    int c = tid & 7;
    int rb = tid >> 3;                      // 0..127

    u64* gm = bits + (size_t)bx * NWORDS;

    // zero guard cells of BOTH buffers (never written again)
    if (tid < LROWS) {
        int i = tid;
        if (i == 0 || i == LROWS - 1) {
            #pragma unroll
            for (int j = 0; j < LSTR; ++j) { Mb[0][i * LSTR + j] = 0; Mb[1][i * LSTR + j] = 0; }
        } else {
            Mb[0][i * LSTR + 0] = 0; Mb[0][i * LSTR + 9] = 0;
            Mb[1][i * LSTR + 0] = 0; Mb[1][i * LSTR + 9] = 0;
        }
    }

    {   // load packed image into padded interior (16B/lane global reads)
        const ulonglong2* s2 = (const ulonglong2*)gm;
        #pragma unroll
        for (int k = 0; k < 2; ++k) {
            int i = k * NTHREADS + tid;     // pair index 0..2047
            ulonglong2 v = s2[i];
            int wi = i * 2;                 // even global word index
            int r = wi >> 3, c2 = wi & 7;
            int li = (r + 1) * LSTR + c2 + 1;
            Mb[0][li] = v.x;
            Mb[0][li + 1] = v.y;
        }
    }

    // init rowblock dirty masks: all interior dirty
    if (tid < 130) {
        Cpb[0][tid] = (tid >= 1 && tid <= 128) ? 0x1FEu : 0u;
        Cpb[1][tid] = 0u;
    }
    if (tid < 3) s_any[tid] = 0;

    unsigned dl = 0x1FEu;                   // owner lane's "last sub-step" byte
    bool prevchg = true;
    int base = (rb * 4 + 1) * LSTR + (c + 1);   // LDS word index of row 4rb, own col

    int it = 0;
    bool done = false;
    for (;;) {
        for (int step = 0; step < 2; ++step) {
            __syncthreads();                // orders prior phase's writes
            if (step == 0 && it > 0) {
                if (s_any[(it + 2) % 3] == 0) { done = true; break; }
            }
            const u64* Ms = Mb[step];
            u64* Md = Mb[step ^ 1];
            const unsigned* CpS = Cpb[step];
            unsigned* CpD = Cpb[step ^ 1];

            unsigned need = ((CpS[rb] | CpS[rb + 1] | CpS[rb + 2]) >> c) & 7u;
            bool chg = false;
            if (need) {
                // rolling 3-row window of (C, E=east-view, W=west-view)
                u64 Ca, Ea, Wa, Cb, Eb, Wb, Cc, Ec, Wc;
                {   int a = base - LSTR;
                    u64 x = Ms[a], mm = Ms[a - 1], pp = Ms[a + 1];
                    Ca = x; Ea = (x >> 1) | (pp << 63); Wa = (x << 1) | (mm >> 63); }
                {   int a = base;
                    u64 x = Ms[a], mm = Ms[a - 1], pp = Ms[a + 1];
                    Cb = x; Eb = (x >> 1) | (pp << 63); Wb = (x << 1) | (mm >> 63); }
                u64 nv0 = 0, nv1 = 0, nv2 = 0, nv3 = 0;

                {   int a = base + LSTR;
                    u64 x = Ms[a], mm = Ms[a - 1], pp = Ms[a + 1];
                    Cc = x; Ec = (x >> 1) | (pp << 63); Wc = (x << 1) | (mm >> 63);
                    if (Cb) nv0 = zs_core(Cb, Ca, Ea, Eb, Ec, Cc, Wc, Wb, Wa, step);
                    chg |= (nv0 != Cb);
                    Ca = Cb; Ea = Eb; Wa = Wb; Cb = Cc; Eb = Ec; Wb = Wc; }
                {   int a = base + 2 * LSTR;
                    u64 x = Ms[a], mm = Ms[a - 1], pp = Ms[a + 1];
                    Cc = x; Ec = (x >> 1) | (pp << 63); Wc = (x << 1) | (mm >> 63);
                    if (Cb) nv1 = zs_core(Cb, Ca, Ea, Eb, Ec, Cc, Wc, Wb, Wa, step);
                    chg |= (nv1 != Cb);
                    Ca = Cb; Ea = Eb; Wa = Wb; Cb = Cc; Eb = Ec; Wb = Wc; }
                {   int a = base + 3 * LSTR;
                    u64 x = Ms[a], mm = Ms[a - 1], pp = Ms[a + 1];
                    Cc = x; Ec = (x >> 1) | (pp << 63); Wc = (x << 1) | (mm >> 63);
                    if (Cb) nv2 = zs_core(Cb, Ca, Ea, Eb, Ec, Cc, Wc, Wb, Wa, step);
                    chg |= (nv2 != Cb);
                    Ca = Cb; Ea = Eb; Wa = Wb; Cb = Cc; Eb = Ec; Wb = Wc; }
                {   int a = base + 4 * LSTR;
                    u64 x = Ms[a], mm = Ms[a - 1], pp = Ms[a + 1];
                    Cc = x; Ec = (x >> 1) | (pp << 63); Wc = (x << 1) | (mm >> 63);
                    if (Cb) nv3 = zs_core(Cb, Ca, Ea, Eb, Ec, Cc, Wc, Wb, Wa, step);
                    chg |= (nv3 != Cb); }

                // Md holds state from 2 phases back; store only if this word-
                // group changed in this phase or the previous one.
                if (chg | prevchg) {
                    Md[base] = nv0;
                    Md[base + LSTR] = nv1;
                    Md[base + 2 * LSTR] = nv2;
                    Md[base + 3 * LSTR] = nv3;
                }
            }
            // need==0 implies prevchg==false (own change would set own Cp bit),
            // so the skip path needs no copy.
            prevchg = chg;

            u64 bal = __ballot(chg);        // 8 rowblocks x 8 cols of this wave
            if (bal && lane == 0) s_any[it % 3] = 1;
            if ((lane & 7) == 0) {          // one owner per rowblock
                unsigned byte = ((unsigned)(bal >> lane) & 0xFFu) << 1;
                CpD[rb + 1] = byte | dl;    // union of last two sub-steps
                dl = byte;
            }
            if (step == 1 && tid == 0) s_any[(it + 1) % 3] = 0;
        }
        if (done || it >= 1024) break;      // uniform; cap is unreachable (ZS
        ++it;                               // converges in <=~260 iters) but
    }                                       // guarantees termination

    {   // publish skeleton (state is in Mb[0]: phase count is even at break)
        ulonglong2* d2 = (ulonglong2*)gm;
        #pragma unroll
        for (int k = 0; k < 2; ++k) {
            int i = k * NTHREADS + tid;
            int wi = i * 2;
            int r = wi >> 3, c2 = wi & 7;
            int li = (r + 1) * LSTR + c2 + 1;
            ulonglong2 v;
            v.x = Mb[0][li];
            v.y = Mb[0][li + 1];
            d2[i] = v;
        }
    }
}

// ---------------- count: 8 strips/image, 128 blocks ----------------
#define STRIPS 8
#define SROWS (HH / STRIPS)   // 64 interior rows per strip
#define SR2 (SROWS + 6)       // + 3-row halo each side

__device__ __forceinline__ u64 ldws(const u64* M, int r, int c) {
    return (c < 0 || c >= WPR) ? 0ULL : M[r * WPR + c];   // rows always in range
}

// radius-3 disk dilation; strip-local r in [3, 3+SROWS)
__device__ __forceinline__ u64 dil3s(const u64* M, int r, int c) {
    u64 cm = ldws(M, r, c - 1), cc = ldws(M, r, c), cp = ldws(M, r, c + 1);
    u64 h = cc
          | (cc >> 1) | (cp << 63)
          | (cc >> 2) | (cp << 62)
          | (cc >> 3) | (cp << 61)
          | (cc << 1) | (cm >> 63)
          | (cc << 2) | (cm >> 62)
          | (cc << 3) | (cm >> 61);
    u64 um = ldws(M, r - 1, c - 1) | ldws(M, r + 1, c - 1) | ldws(M, r - 2, c - 1) | ldws(M, r + 2, c - 1);
    u64 uc = ldws(M, r - 1, c    ) | ldws(M, r + 1, c    ) | ldws(M, r - 2, c    ) | ldws(M, r + 2, c    );
    u64 up = ldws(M, r - 1, c + 1) | ldws(M, r + 1, c + 1) | ldws(M, r - 2, c + 1) | ldws(M, r + 2, c + 1);
    h |= uc
       | (uc >> 1) | (up << 63)
       | (uc >> 2) | (up << 62)
       | (uc << 1) | (um >> 63)
       | (uc << 2) | (um >> 62);
    h |= ldws(M, r - 3, c) | ldws(M, r + 3, c);
    return h;
}

__global__ __launch_bounds__(256)
void count_kernel(const u64* __restrict__ skel, int* __restrict__ cnt) {
    __shared__ u64 P[SR2 * WPR];
    __shared__ u64 G[SR2 * WPR];
    __shared__ int acc[4];

    int b = blockIdx.x / STRIPS;
    int s = blockIdx.x % STRIPS;
    int tid = threadIdx.x;
    int r0 = s * SROWS - 3;                 // global row of strip-local row 0

    const u64* sp = skel + (size_t)b * NWORDS;
    const u64* sg = skel + (size_t)(NB + b) * NWORDS;
    for (int i = tid; i < SR2 * WPR; i += 256) {
        int gr = r0 + (i >> 3);
        bool in = (gr >= 0 && gr < HH);
        int gi = gr * WPR + (i & 7);
        P[i] = in ? sp[gi] : 0ULL;
        G[i] = in ? sg[gi] : 0ULL;
    }
    if (tid < 4) acc[tid] = 0;
    __syncthreads();

    int cp = 0, cg = 0, tp = 0, fnh = 0;
    #pragma unroll
    for (int k = 0; k < 2; ++k) {
        int w = k * 256 + tid;              // 0..511 interior words
        int r = (w >> 3) + 3, c = w & 7;
        u64 pw = P[r * WPR + c], gw = G[r * WPR + c];
        cp  += __popcll(pw);
        cg  += __popcll(gw);
        tp  += __popcll(pw & dil3s(G, r, c));
        fnh += __popcll(gw & dil3s(P, r, c));
    }
    #pragma unroll
    for (int o = 32; o > 0; o >>= 1) {
        cp  += __shfl_down(cp, o);
        cg  += __shfl_down(cg, o);
        tp  += __shfl_down(tp, o);
        fnh += __shfl_down(fnh, o);
    }
    if ((tid & 63) == 0) {
        atomicAdd(&acc[0], cp);
        atomicAdd(&acc[1], cg);
        atomicAdd(&acc[2], tp);
        atomicAdd(&acc[3], fnh);
    }
    __syncthreads();
    if (tid < 4) atomicAdd(&cnt[b * 4 + tid], acc[tid]);
}

__global__ void ccq_reduce(const int* __restrict__ cnt, float* __restrict__ out) {
    int k = threadIdx.x;
    if (k < 3) {
        float s = 0.0f;
        for (int b = 0; b < NB; ++b) {
            float TP = (float)cnt[b * 4 + 2];
            float FP = (float)(cnt[b * 4 + 0] - cnt[b * 4 + 2]);
            float FN = (float)(cnt[b * 4 + 1] - cnt[b * 4 + 3]);
            float v = (k == 0) ? TP / (TP + FP + 1e-12f)
                    : (k == 1) ? TP / (TP + FN + 1e-12f)
                               : TP / (TP + FP + FN + 1e-12f);
            s += v;
        }
        out[k] = s * (1.0f / NB);
    }
}

extern "C" void kernel_launch(void* const* d_in, const int* in_sizes, int n_in,
                              void* d_out, int out_size, void* d_ws, size_t ws_size,
                              hipStream_t stream) {
    (void)in_sizes; (void)n_in; (void)out_size; (void)ws_size;
    const float* y_pred = (const float*)d_in[0];
    const float* y_true = (const float*)d_in[1];
    float* out = (float*)d_out;

    u64* bits = (u64*)d_ws;                               // 1 MB: packed, then skeleton
    int* cnt = (int*)((char*)d_ws + (size_t)2 * NB * NWORDS * sizeof(u64)); // 64 ints

    hipLaunchKernelGGL(pack_kernel, dim3(2 * NB * HW / 16 / 256), dim3(256), 0, stream,
                       y_pred, y_true, bits, cnt);
    hipLaunchKernelGGL(skel_kernel, dim3(2 * NB), dim3(NTHREADS), 0, stream, bits);
    hipLaunchKernelGGL(count_kernel, dim3(NB * STRIPS), dim3(256), 0, stream,
                       bits, cnt);
    hipLaunchKernelGGL(ccq_reduce, dim3(1), dim3(64), 0, stream, cnt, out);
}